// Round 2
// baseline (412.471 us; speedup 1.0000x reference)
//
#include <hip/hip_runtime.h>

// B=2, Hi=Wi=64, Di=32, C=16, F=8, strides (2,2,2), k=3x3x3, Ho=Wo=128, Do=64.
constexpr int Bc  = 2;
constexpr int HiC = 64, WiC = 64, DiC = 32;
constexpr int Cc  = 16, Fc  = 8;
constexpr int HoC = 128, WoC = 128, DoC = 64;
constexpr int NW  = 27 * Fc * Cc;   // 3456 kernel weights (13.5 KiB)

// Wave = 2 same-parity columns (kh/kw validity wave-uniform); lane = (half, rr).
// Lane owns doE (dn even -> kd 0,2) and doO (dn odd -> kd 1): 3 lane-dense taps.
// Valid spatial positions = {1,2,4} by (ho,wo) parity -> wave-uniform branch,
// explicitly software-pipelined: loads of position p+1 issue under FMAs of p.
// Invalid taps load from a 256B zeroed scratch region (branchless ptr select).
__global__ __launch_bounds__(256, 3)
void sconv3dt_kernel(const float* __restrict__ images,
                     const int*   __restrict__ base_plane,
                     const float* __restrict__ kern,
                     float*       __restrict__ out,
                     const float* __restrict__ zpad) {
    __shared__ float wlds[NW];
    for (int i = threadIdx.x; i < NW; i += 256) wlds[i] = kern[i];
    __syncthreads();

    const int t    = threadIdx.x;
    const int wv   = t >> 6;
    const int lane = t & 63;
    const int half = lane >> 5;
    const int rr   = lane & 31;
    const int b    = blockIdx.z;
    const int ho   = blockIdx.y;
    const int wo   = (blockIdx.x << 3) + (wv & 1) + ((wv >> 1) << 2) + (half << 1);

    const int bp_col = base_plane[(b * HoC + ho) * WoC + wo];
    const int q   = (bp_col + 1) & 1;
    const int doE = 2 * rr + q;          // (bp+do+1) even -> kd in {0,2}
    const int doO = 2 * rr + 1 - q;      // (bp+do+1) odd  -> kd = 1
    const int hEc = (bp_col + doE + 1) >> 1;   // di(kd=0) = hEc - bpg; kd=2: -1
    const int hOc = (bp_col + doO) >> 1;       // di(kd=1) = hOc - bpg

    const int  hoOdd = ho & 1;
    const int  woOdd = wo & 1;           // wave-uniform (columns same parity)
    const int  khA   = hoOdd ? 0 : 1;    // khB = 2 (only when hoOdd, always valid)
    const int  kwA   = woOdd ? 0 : 1;    // kwB = 2 (only when woOdd, always valid)
    const bool mhA   = !hoOdd || (ho + 1 < HoC);   // block-uniform
    const bool mwA   = !woOdd || (wo + 1 < WoC);   // per-lane (edge only)
    const int  npos  = (hoOdd ? 2 : 1) * (woOdd ? 2 : 1);   // wave-uniform

    float accE[Fc] = {0, 0, 0, 0, 0, 0, 0, 0};
    float accO[Fc] = {0, 0, 0, 0, 0, 0, 0, 0};

    auto LOAD = [&](int kh, int kw, bool mhw, float4* vv, const float** wbp) {
        const int hn = ho + 1 - kh;              // even by construction
        const int wn = wo + 1 - kw;
        int hi = hn >> 1; hi = hi < 0 ? 0 : (hi > HiC - 1 ? HiC - 1 : hi);
        int wi = wn >> 1; wi = wi < 0 ? 0 : (wi > WiC - 1 ? WiC - 1 : wi);
        const int bpg = base_plane[(b * HoC + 2 * hi) * WoC + 2 * wi] >> 1;
        const float* ibase =
            images + (size_t)((b * HiC + hi) * WiC + wi) * (DiC * Cc);
        const int dE0 = hEc - bpg;   // kd = 0
        const int dE2 = dE0 - 1;     // kd = 2
        const int dO1 = hOc - bpg;   // kd = 1
        const float4* pE0 = (const float4*)(
            (mhw && dE0 >= 0 && dE0 < DiC) ? ibase + (size_t)dE0 * Cc : zpad);
        const float4* pE2 = (const float4*)(
            (mhw && dE2 >= 0 && dE2 < DiC) ? ibase + (size_t)dE2 * Cc : zpad);
        const float4* pO1 = (const float4*)(
            (mhw && dO1 >= 0 && dO1 < DiC) ? ibase + (size_t)dO1 * Cc : zpad);
        vv[0] = pE0[0]; vv[1]  = pE0[1]; vv[2]  = pE0[2]; vv[3]  = pE0[3];
        vv[4] = pE2[0]; vv[5]  = pE2[1]; vv[6]  = pE2[2]; vv[7]  = pE2[3];
        vv[8] = pO1[0]; vv[9]  = pO1[1]; vv[10] = pO1[2]; vv[11] = pO1[3];
        *wbp = wlds + (kh * 3 + kw) * (3 * Fc * Cc);
    };

    auto dot4 = [](float4 a, float4 w) {
        return a.x * w.x + a.y * w.y + a.z * w.z + a.w * w.w;
    };

    auto FMA = [&](const float4* vv, const float* wbp) {
        #pragma unroll
        for (int f = 0; f < Fc; ++f) {
            const float4* w0 = (const float4*)(wbp + f * 16);         // kd=0
            const float4* w1 = (const float4*)(wbp + 128 + f * 16);   // kd=1
            const float4* w2 = (const float4*)(wbp + 256 + f * 16);   // kd=2
            accE[f] += dot4(vv[0], w0[0]) + dot4(vv[1], w0[1])
                     + dot4(vv[2], w0[2]) + dot4(vv[3], w0[3])
                     + dot4(vv[4], w2[0]) + dot4(vv[5], w2[1])
                     + dot4(vv[6], w2[2]) + dot4(vv[7], w2[3]);
            accO[f] += dot4(vv[8], w1[0]) + dot4(vv[9], w1[1])
                     + dot4(vv[10], w1[2]) + dot4(vv[11], w1[3]);
        }
    };

    float4 va[12], vb[12];
    const float *wa, *wb;
    LOAD(khA, kwA, mhA && mwA, va, &wa);
    if (npos == 1) {
        FMA(va, wa);
    } else if (npos == 2) {
        // hoOdd,!woOdd: (khB,kwA) m=true.  !hoOdd,woOdd: (khA,kwB) m=true.
        const int kh2 = hoOdd ? 2 : khA;
        const int kw2 = hoOdd ? kwA : 2;
        LOAD(kh2, kw2, true, vb, &wb);
        FMA(va, wa);
        FMA(vb, wb);
    } else {   // npos == 4 (hoOdd && woOdd)
        LOAD(khA, 2, mhA, vb, &wb);      // (khA,kwB)
        FMA(va, wa);
        LOAD(2, kwA, mwA, va, &wa);      // (khB,kwA)
        FMA(vb, wb);
        LOAD(2, 2, true, vb, &wb);       // (khB,kwB)
        FMA(va, wa);
        FMA(vb, wb);
    }

    float* op = out + (size_t)((b * HoC + ho) * WoC + wo) * (DoC * Fc);
    float4* oE = (float4*)(op + doE * Fc);
    oE[0] = make_float4(accE[0], accE[1], accE[2], accE[3]);
    oE[1] = make_float4(accE[4], accE[5], accE[6], accE[7]);
    float4* oO = (float4*)(op + doO * Fc);
    oO[0] = make_float4(accO[0], accO[1], accO[2], accO[3]);
    oO[1] = make_float4(accO[4], accO[5], accO[6], accO[7]);
}

extern "C" void kernel_launch(void* const* d_in, const int* in_sizes, int n_in,
                              void* d_out, int out_size, void* d_ws, size_t ws_size,
                              hipStream_t stream) {
    const float* images     = (const float*)d_in[0];
    const int*   base_plane = (const int*)d_in[1];
    const float* kern       = (const float*)d_in[2];
    float* out = (float*)d_out;

    // 256 B of zeros in workspace: branchless OOB-tap target (re-poisoned to
    // 0xAA before every timed launch, so memset every call).
    hipMemsetAsync(d_ws, 0, 256, stream);

    dim3 grid(WoC / 8, HoC, Bc);   // 16 x 128 x 2 = 4096 blocks
    dim3 block(256);
    hipLaunchKernelGGL(sconv3dt_kernel, grid, block, 0, stream,
                       images, base_plane, kern, out, (const float*)d_ws);
}

// Round 3
// 135.304 us; speedup vs baseline: 3.0485x; 3.0485x over previous
//
#include <hip/hip_runtime.h>

// B=2, Hi=Wi=64, Di=32, C=16, F=8, strides (2,2,2), k=3x3x3, Ho=Wo=128, Do=64.
constexpr int Bc  = 2;
constexpr int HiC = 64, WiC = 64, DiC = 32;
constexpr int Cc  = 16, Fc  = 8;
constexpr int HoC = 128, WoC = 128, DoC = 64;

// One input row (16 channels) for one tap. Named members only — round-2's
// pointer-out-param float4 arrays were demoted to scratch (822 MB WRITE_SIZE).
struct Tap { float4 a, b, c, d; };

__device__ __forceinline__ Tap load_tap(const float4* __restrict__ p) {
    Tap t; t.a = p[0]; t.b = p[1]; t.c = p[2]; t.d = p[3]; return t;
}

// w[] has a wave-uniform address -> scalar loads; v_fma with 1 SGPR operand.
__device__ __forceinline__ float dot16(const Tap& t, const float* __restrict__ w) {
    return t.a.x * w[0]  + t.a.y * w[1]  + t.a.z * w[2]  + t.a.w * w[3]
         + t.b.x * w[4]  + t.b.y * w[5]  + t.b.z * w[6]  + t.b.w * w[7]
         + t.c.x * w[8]  + t.c.y * w[9]  + t.c.z * w[10] + t.c.w * w[11]
         + t.d.x * w[12] + t.d.y * w[13] + t.d.z * w[14] + t.d.w * w[15];
}

struct Pos { const float4* pE0; const float4* pE2; const float4* pO1; int kidx; };

// Wave = 2 same-parity columns; lane = (half, rr) owns depth pair (doE, doO).
// 3 kd-taps per position are lane-dense, kd wave-uniform (parity construction).
// Weights: direct uniform reads from kern -> SGPRs (no LDS in this kernel).
__global__ __launch_bounds__(256, 3)
void sconv3dt_kernel(const float* __restrict__ images,
                     const int*   __restrict__ base_plane,
                     const float* __restrict__ kern,
                     float*       __restrict__ out,
                     const float* __restrict__ zpad) {
    const int t    = threadIdx.x;
    const int wv   = t >> 6;
    const int lane = t & 63;
    const int half = lane >> 5;
    const int rr   = lane & 31;
    const int b    = blockIdx.z;
    const int ho   = blockIdx.y;
    const int wo   = (blockIdx.x << 3) + (wv & 1) + ((wv >> 1) << 2) + (half << 1);

    const int bp_col = base_plane[(b * HoC + ho) * WoC + wo];
    const int q   = (bp_col + 1) & 1;
    const int doE = 2 * rr + q;            // (bp+do+1) even -> kd in {0,2}
    const int doO = 2 * rr + 1 - q;        // (bp+do+1) odd  -> kd = 1
    const int hEc = (bp_col + doE + 1) >> 1;   // di(kd=0) = hEc - bpg; kd=2: -1
    const int hOc = (bp_col + doO) >> 1;       // di(kd=1) = hOc - bpg

    const int  hoOdd = ho & 1;
    const int  woOdd = wo & 1;             // wave-uniform (columns same parity)
    const int  khA   = hoOdd ? 0 : 1;
    const int  kwA   = woOdd ? 0 : 1;
    const bool mhA   = !hoOdd || (ho + 1 < HoC);
    const bool mwA   = !woOdd || (wo + 1 < WoC);   // per-lane at right edge only
    const int  npos  = (hoOdd ? 2 : 1) * (woOdd ? 2 : 1);   // wave-uniform

    auto prep = [&](int kh, int kw, bool mhw) -> Pos {
        const int hn = ho + 1 - kh;        // even by construction
        const int wn = wo + 1 - kw;
        int hi = hn >> 1; hi = hi < 0 ? 0 : (hi > HiC - 1 ? HiC - 1 : hi);
        int wi = wn >> 1; wi = wi < 0 ? 0 : (wi > WiC - 1 ? WiC - 1 : wi);
        const int bpg = base_plane[(b * HoC + 2 * hi) * WoC + 2 * wi] >> 1;
        const float* ibase =
            images + (size_t)((b * HiC + hi) * WiC + wi) * (DiC * Cc);
        const int dE0 = hEc - bpg;         // kd = 0
        const int dE2 = dE0 - 1;           // kd = 2
        const int dO1 = hOc - bpg;         // kd = 1
        Pos P;
        P.pE0 = (const float4*)((mhw && dE0 >= 0 && dE0 < DiC)
                                    ? ibase + (size_t)dE0 * Cc : zpad);
        P.pE2 = (const float4*)((mhw && dE2 >= 0 && dE2 < DiC)
                                    ? ibase + (size_t)dE2 * Cc : zpad);
        P.pO1 = (const float4*)((mhw && dO1 >= 0 && dO1 < DiC)
                                    ? ibase + (size_t)dO1 * Cc : zpad);
        P.kidx = __builtin_amdgcn_readfirstlane((kh * 3 + kw) * (3 * Fc * Cc));
        return P;
    };

    float accE[Fc] = {0, 0, 0, 0, 0, 0, 0, 0};
    float accO[Fc] = {0, 0, 0, 0, 0, 0, 0, 0};

    auto FMA = [&](const Tap& tE0, const Tap& tE2, const Tap& tO1, int kidx) {
        const float* __restrict__ w = kern + kidx;   // uniform -> s_load
        #pragma unroll
        for (int f = 0; f < Fc; ++f) {
            accE[f] += dot16(tE0, w + f * 16)              // kd=0
                     + dot16(tE2, w + 2 * 128 + f * 16);   // kd=2
            accO[f] += dot16(tO1, w + 1 * 128 + f * 16);   // kd=1
        }
    };

    Pos P0 = prep(khA, kwA, mhA && mwA);
    Tap e0 = load_tap(P0.pE0), e2 = load_tap(P0.pE2), o1 = load_tap(P0.pO1);
    if (npos == 1) {
        FMA(e0, e2, o1, P0.kidx);
    } else if (npos == 2) {
        // hoOdd,!woOdd: (2,kwA) always valid.  !hoOdd,woOdd: (khA,2) always valid.
        const int kh2 = hoOdd ? 2 : khA;
        const int kw2 = hoOdd ? kwA : 2;
        Pos P1 = prep(kh2, kw2, true);
        Tap f0 = load_tap(P1.pE0), f2 = load_tap(P1.pE2), g1 = load_tap(P1.pO1);
        FMA(e0, e2, o1, P0.kidx);
        FMA(f0, f2, g1, P1.kidx);
    } else {   // npos == 4 (hoOdd && woOdd)
        Pos P1 = prep(khA, 2, mhA);
        Pos P2 = prep(2, kwA, mwA);
        Pos P3 = prep(2, 2, true);
        FMA(e0, e2, o1, P0.kidx);
        e0 = load_tap(P1.pE0); e2 = load_tap(P1.pE2); o1 = load_tap(P1.pO1);
        FMA(e0, e2, o1, P1.kidx);
        e0 = load_tap(P2.pE0); e2 = load_tap(P2.pE2); o1 = load_tap(P2.pO1);
        FMA(e0, e2, o1, P2.kidx);
        e0 = load_tap(P3.pE0); e2 = load_tap(P3.pE2); o1 = load_tap(P3.pO1);
        FMA(e0, e2, o1, P3.kidx);
    }

    float* op = out + (size_t)((b * HoC + ho) * WoC + wo) * (DoC * Fc);
    float4* oE = (float4*)(op + doE * Fc);
    oE[0] = make_float4(accE[0], accE[1], accE[2], accE[3]);
    oE[1] = make_float4(accE[4], accE[5], accE[6], accE[7]);
    float4* oO = (float4*)(op + doO * Fc);
    oO[0] = make_float4(accO[0], accO[1], accO[2], accO[3]);
    oO[1] = make_float4(accO[4], accO[5], accO[6], accO[7]);
}

extern "C" void kernel_launch(void* const* d_in, const int* in_sizes, int n_in,
                              void* d_out, int out_size, void* d_ws, size_t ws_size,
                              hipStream_t stream) {
    const float* images     = (const float*)d_in[0];
    const int*   base_plane = (const int*)d_in[1];
    const float* kern       = (const float*)d_in[2];
    float* out = (float*)d_out;

    // 256 B zeros in workspace: branchless OOB-tap target (ws re-poisoned to
    // 0xAA before every timed launch, so memset on every call).
    hipMemsetAsync(d_ws, 0, 256, stream);

    dim3 grid(WoC / 8, HoC, Bc);   // 16 x 128 x 2 = 4096 blocks
    dim3 block(256);
    hipLaunchKernelGGL(sconv3dt_kernel, grid, block, 0, stream,
                       images, base_plane, kern, out, (const float*)d_ws);
}